// Round 7
// baseline (128.518 us; speedup 1.0000x reference)
//
#include <hip/hip_runtime.h>

#define HIST_BINS 8192             // 2^13 bins: top-13 bits of monotonic key
#define HIST_BYTES (HIST_BINS * 4)
#define KEY_SHIFT 19
#define NPART 8                    // partial global histograms (bounds atomic chains)
#define RECALL_LO_C 0.95
#define GRID1 1024                 // 4 blocks/CU @ 32KB LDS -> 16 waves/CU

// ---------------------------------------------------------------------------
// Pass 1: CE partial sum, positive count, LDS-privatized 2^13-bin histogram
// (packed [pos<<16 | neg], 32 KB LDS -> 4 blocks/CU). Wave-contiguous
// 8x-unrolled loads keep 16 vmem ops in flight per thread; grid sized so each
// wave runs exactly one chunk (4096 waves x 512 float4 = N/4).
// Flush goes to one of NPART partial global histograms (chains <= 128),
// rotated per-block to avoid lockstep contention.
// ---------------------------------------------------------------------------
__global__ __launch_bounds__(256) void pass1_kernel(
    const float* __restrict__ pred, const int* __restrict__ tgt,
    unsigned int* __restrict__ ghist, double* __restrict__ ce_sum,
    unsigned int* __restrict__ pos_cnt, int n)
{
    __shared__ unsigned int lhist[HIST_BINS];   // 32 KB

    uint4* lh4 = (uint4*)lhist;
    for (int b = threadIdx.x; b < HIST_BINS / 4; b += 256)
        lh4[b] = make_uint4(0u, 0u, 0u, 0u);
    __syncthreads();

    float ce = 0.0f;
    unsigned int pc = 0;

    const int tid      = blockIdx.x * blockDim.x + threadIdx.x;
    const int nthreads = gridDim.x * blockDim.x;
    const int lane     = threadIdx.x & 63;
    const int gwid     = tid >> 6;
    const int nwaves   = nthreads >> 6;
    const int n4       = n >> 2;

    const float4* p4 = (const float4*)pred;
    const int4*   t4 = (const int4*)tgt;

    // each wave owns contiguous 512-float4 (8 KB) chunks; with GRID1=1024 the
    // loop body executes exactly once per wave for N = 8.4M
    for (int wstart = gwid * 512; wstart < n4; wstart += nwaves * 512) {
        if (wstart + 512 <= n4) {
            float4 x[8];
            int4   t[8];
#pragma unroll
            for (int j = 0; j < 8; ++j) x[j] = p4[wstart + j * 64 + lane];
#pragma unroll
            for (int j = 0; j < 8; ++j) t[j] = t4[wstart + j * 64 + lane];
#pragma unroll
            for (int j = 0; j < 8; ++j) {
                float xs[4] = {x[j].x, x[j].y, x[j].z, x[j].w};
                int   ts[4] = {t[j].x, t[j].y, t[j].z, t[j].w};
#pragma unroll
                for (int c = 0; c < 4; ++c) {
                    float xv = xs[c];
                    ce += fmaxf(xv, 0.0f) - xv * (float)ts[c]
                        + __logf(1.0f + __expf(-fabsf(xv)));
                    pc += (unsigned int)ts[c];
                    unsigned int u = __float_as_uint(xv);
                    int          m = (int)u >> 31;
                    unsigned int key = u ^ (0x80000000u | (unsigned int)m);
                    atomicAdd(&lhist[key >> KEY_SHIFT], ts[c] ? 65536u : 1u);
                }
            }
        } else {
            for (int j = 0; j < 8; ++j) {
                int idx = wstart + j * 64 + lane;
                if (idx < n4) {
                    float4 x = p4[idx];
                    int4   t = t4[idx];
                    float xs[4] = {x.x, x.y, x.z, x.w};
                    int   ts[4] = {t.x, t.y, t.z, t.w};
                    for (int c = 0; c < 4; ++c) {
                        float xv = xs[c];
                        ce += fmaxf(xv, 0.0f) - xv * (float)ts[c]
                            + __logf(1.0f + __expf(-fabsf(xv)));
                        pc += (unsigned int)ts[c];
                        unsigned int u = __float_as_uint(xv);
                        int          m = (int)u >> 31;
                        unsigned int key = u ^ (0x80000000u | (unsigned int)m);
                        atomicAdd(&lhist[key >> KEY_SHIFT], ts[c] ? 65536u : 1u);
                    }
                }
            }
        }
    }
    // scalar tail for n % 4 (none for N = 8.4M)
    for (int i = (n4 << 2) + tid; i < n; i += nthreads) {
        float xv = pred[i];
        int   ti = tgt[i];
        ce += fmaxf(xv, 0.0f) - xv * (float)ti
            + __logf(1.0f + __expf(-fabsf(xv)));
        pc += (unsigned int)ti;
        unsigned int u = __float_as_uint(xv);
        int          m = (int)u >> 31;
        unsigned int key = u ^ (0x80000000u | (unsigned int)m);
        atomicAdd(&lhist[key >> KEY_SHIFT], ti ? 65536u : 1u);
    }

    // CE / pos-count: wave reduce, one atomic per wave
    for (int off = 32; off > 0; off >>= 1) {
        ce += __shfl_down(ce, off);
        pc += __shfl_down(pc, off);
    }
    if ((threadIdx.x & 63) == 0) {
        atomicAdd(ce_sum, (double)ce);
        atomicAdd(pos_cnt, pc);
    }

    // flush LDS histogram into this block's partial global histogram,
    // starting bin rotated per-block to decorrelate atomic targets
    __syncthreads();
    unsigned int* gp = ghist + (blockIdx.x & (NPART - 1)) * HIST_BINS;
    const int nq  = HIST_BINS / 4;
    const int rot = (blockIdx.x * 8) & (nq - 1);
    for (int i = threadIdx.x; i < nq; i += 256) {
        int b = (i + rot) & (nq - 1);
        uint4 v = lh4[b];
        if (v.x) atomicAdd(&gp[4 * b + 0], v.x);
        if (v.y) atomicAdd(&gp[4 * b + 1], v.y);
        if (v.z) atomicAdd(&gp[4 * b + 2], v.z);
        if (v.w) atomicAdd(&gp[4 * b + 3], v.w);
    }
}

// ---------------------------------------------------------------------------
// Pass 2 (single block, 256 threads): sum NPART partials while loading each
// thread's 32-bin chunk into registers, Hillis-Steele scan for the positive
// prefix, then the descending-bin pAUC sum:
//   bin contribution = ng * E_f~U(0,1)[ max(0, (CP - 0.95P) + p*f) ]
// pAUC = S/(P*Ng);  loss = 0.5*CE_mean + 0.5*(1 - clip(pAUC/0.1,0,1)^2)
// ---------------------------------------------------------------------------
__global__ __launch_bounds__(256) void pass2_kernel(
    const unsigned int* __restrict__ hist, const double* __restrict__ ce_sum,
    const unsigned int* __restrict__ pos_cnt, float* __restrict__ out, int n)
{
    __shared__ double chunk_pos[256];
    __shared__ double sred[256];

    const int tid = threadIdx.x;
    const int lo  = HIST_BINS - (tid + 1) * 32;   // thread's 32-bin chunk

    // load chunk, summing the NPART partials (packed add: class sums < 65536)
    const uint4* h4 = (const uint4*)hist;
    uint4 q[8];
#pragma unroll
    for (int j = 0; j < 8; ++j) {
        uint4 s = make_uint4(0u, 0u, 0u, 0u);
#pragma unroll
        for (int p = 0; p < NPART; ++p) {
            uint4 v = h4[p * (HIST_BINS / 4) + lo / 4 + j];
            s.x += v.x; s.y += v.y; s.z += v.z; s.w += v.w;
        }
        q[j] = s;
    }

    // phase 1: positives per chunk
    double psum = 0.0;
#pragma unroll
    for (int j = 0; j < 8; ++j) {
        psum += (double)(q[j].x >> 16) + (double)(q[j].y >> 16)
              + (double)(q[j].z >> 16) + (double)(q[j].w >> 16);
    }
    chunk_pos[tid] = psum;
    __syncthreads();

    // phase 2: Hillis-Steele inclusive scan over descending-chunk order
    double v = psum;
    for (int s = 1; s < 256; s <<= 1) {
        double add = (tid >= s) ? chunk_pos[tid - s] : 0.0;
        __syncthreads();
        v += add;
        chunk_pos[tid] = v;
        __syncthreads();
    }
    double CP = v - psum;   // exclusive prefix: positives strictly above chunk

    const unsigned int P = *pos_cnt;
    const double T = RECALL_LO_C * (double)P;

    // phase 3: walk chunk descending (bin lo+4j+k, j=7..0, k=3..0)
    double S = 0.0;
#pragma unroll
    for (int j = 7; j >= 0; --j) {
        unsigned int e[4] = {q[j].x, q[j].y, q[j].z, q[j].w};
#pragma unroll
        for (int k = 3; k >= 0; --k) {
            unsigned int h = e[k];
            double p  = (double)(h >> 16);
            double ng = (double)(h & 0xFFFFu);
            if (ng > 0.0) {
                double a = CP - T;
                double contrib;
                if (a >= 0.0) {
                    contrib = a + 0.5 * p;
                } else {
                    double ac = a + p;
                    contrib = (ac > 0.0 && p > 0.0) ? (ac * ac) / (2.0 * p) : 0.0;
                }
                S += ng * contrib;
            }
            CP += p;
        }
    }
    sred[tid] = S;
    __syncthreads();
    for (int s = 128; s > 0; s >>= 1) {
        if (tid < s) sred[tid] += sred[tid + s];
        __syncthreads();
    }

    if (tid == 0) {
        double Ng = (double)n - (double)P;
        double pauc = 0.0;
        if (P > 0 && Ng > 0.0) pauc = sred[0] / ((double)P * Ng);
        double avg = pauc / (2.0 * (1.0 - RECALL_LO_C));   // pauc / 0.1
        avg = fmin(fmax(avg, 0.0), 1.0);
        double ce = *ce_sum / (double)n;
        out[0] = (float)(0.5 * ce + 0.5 * (1.0 - avg * avg));
    }
}

extern "C" void kernel_launch(void* const* d_in, const int* in_sizes, int n_in,
                              void* d_out, int out_size, void* d_ws, size_t ws_size,
                              hipStream_t stream)
{
    const float* pred = (const float*)d_in[0];
    const int*   tgt  = (const int*)d_in[1];
    const int n = in_sizes[0];  // predictions is (N,1) -> N elements

    unsigned int* ghist   = (unsigned int*)d_ws;                       // NPART x HIST_BINS
    double*       ce_sum  = (double*)((char*)d_ws + NPART * HIST_BYTES);
    unsigned int* pos_cnt = (unsigned int*)((char*)d_ws + NPART * HIST_BYTES + 8);

    hipMemsetAsync(d_ws, 0, NPART * HIST_BYTES + 16, stream);

    pass1_kernel<<<GRID1, 256, 0, stream>>>(pred, tgt, ghist, ce_sum, pos_cnt, n);
    pass2_kernel<<<1, 256, 0, stream>>>(ghist, ce_sum, pos_cnt, (float*)d_out, n);
}

// Round 8
// 74.021 us; speedup vs baseline: 1.7362x; 1.7362x over previous
//
#include <hip/hip_runtime.h>

#define HIST_BINS 2048             // 2^11 bins: top-11 bits of monotonic key
#define HIST_BYTES (HIST_BINS * 4)
#define KEY_SHIFT 21
#define NPART 16                   // partial global histograms (chains <= 32)
#define RECALL_LO_C 0.95
#define GRID1 512                  // empirical winner (R6): 2 blocks/CU

// ---------------------------------------------------------------------------
// Pass 1: CE partial sum, positive count, LDS-privatized 2^11-bin histogram
// (packed [pos<<16 | neg], 8 KB LDS). Wave-contiguous 8x-unrolled loads keep
// 16 vmem ops in flight per thread. Flush = 512 x 2048 ~ 1.05M global atomics
// (3.5x fewer than R6) into NPART partials, rotated per block.
// Overflow audit: per-block per-class hot bin ~311 (<65535); per-partial
// per-class ~10k (<65535); final per-class sums done UNPACKED in pass2.
// ---------------------------------------------------------------------------
__global__ __launch_bounds__(256) void pass1_kernel(
    const float* __restrict__ pred, const int* __restrict__ tgt,
    unsigned int* __restrict__ ghist, double* __restrict__ ce_sum,
    unsigned int* __restrict__ pos_cnt, int n)
{
    __shared__ unsigned int lhist[HIST_BINS];   // 8 KB

    uint4* lh4 = (uint4*)lhist;
    for (int b = threadIdx.x; b < HIST_BINS / 4; b += 256)
        lh4[b] = make_uint4(0u, 0u, 0u, 0u);
    __syncthreads();

    float ce = 0.0f;
    unsigned int pc = 0;

    const int tid      = blockIdx.x * blockDim.x + threadIdx.x;
    const int nthreads = gridDim.x * blockDim.x;
    const int lane     = threadIdx.x & 63;
    const int gwid     = tid >> 6;
    const int nwaves   = nthreads >> 6;
    const int n4       = n >> 2;

    const float4* p4 = (const float4*)pred;
    const int4*   t4 = (const int4*)tgt;

    // each wave owns contiguous 512-float4 (8 KB) chunks -> 2 chunks per wave
    for (int wstart = gwid * 512; wstart < n4; wstart += nwaves * 512) {
        if (wstart + 512 <= n4) {
            float4 x[8];
            int4   t[8];
#pragma unroll
            for (int j = 0; j < 8; ++j) x[j] = p4[wstart + j * 64 + lane];
#pragma unroll
            for (int j = 0; j < 8; ++j) t[j] = t4[wstart + j * 64 + lane];
#pragma unroll
            for (int j = 0; j < 8; ++j) {
                float xs[4] = {x[j].x, x[j].y, x[j].z, x[j].w};
                int   ts[4] = {t[j].x, t[j].y, t[j].z, t[j].w};
#pragma unroll
                for (int c = 0; c < 4; ++c) {
                    float xv = xs[c];
                    ce += fmaxf(xv, 0.0f) - xv * (float)ts[c]
                        + __logf(1.0f + __expf(-fabsf(xv)));
                    pc += (unsigned int)ts[c];
                    unsigned int u = __float_as_uint(xv);
                    int          m = (int)u >> 31;
                    unsigned int key = u ^ (0x80000000u | (unsigned int)m);
                    atomicAdd(&lhist[key >> KEY_SHIFT], ts[c] ? 65536u : 1u);
                }
            }
        } else {
            for (int j = 0; j < 8; ++j) {
                int idx = wstart + j * 64 + lane;
                if (idx < n4) {
                    float4 x = p4[idx];
                    int4   t = t4[idx];
                    float xs[4] = {x.x, x.y, x.z, x.w};
                    int   ts[4] = {t.x, t.y, t.z, t.w};
                    for (int c = 0; c < 4; ++c) {
                        float xv = xs[c];
                        ce += fmaxf(xv, 0.0f) - xv * (float)ts[c]
                            + __logf(1.0f + __expf(-fabsf(xv)));
                        pc += (unsigned int)ts[c];
                        unsigned int u = __float_as_uint(xv);
                        int          m = (int)u >> 31;
                        unsigned int key = u ^ (0x80000000u | (unsigned int)m);
                        atomicAdd(&lhist[key >> KEY_SHIFT], ts[c] ? 65536u : 1u);
                    }
                }
            }
        }
    }
    // scalar tail for n % 4 (none for N = 8.4M)
    for (int i = (n4 << 2) + tid; i < n; i += nthreads) {
        float xv = pred[i];
        int   ti = tgt[i];
        ce += fmaxf(xv, 0.0f) - xv * (float)ti
            + __logf(1.0f + __expf(-fabsf(xv)));
        pc += (unsigned int)ti;
        unsigned int u = __float_as_uint(xv);
        int          m = (int)u >> 31;
        unsigned int key = u ^ (0x80000000u | (unsigned int)m);
        atomicAdd(&lhist[key >> KEY_SHIFT], ti ? 65536u : 1u);
    }

    // CE / pos-count: wave reduce, one atomic per wave
    for (int off = 32; off > 0; off >>= 1) {
        ce += __shfl_down(ce, off);
        pc += __shfl_down(pc, off);
    }
    if ((threadIdx.x & 63) == 0) {
        atomicAdd(ce_sum, (double)ce);
        atomicAdd(pos_cnt, pc);
    }

    // flush LDS histogram into this block's partial (rotated start)
    __syncthreads();
    unsigned int* gp = ghist + (blockIdx.x & (NPART - 1)) * HIST_BINS;
    const int nq  = HIST_BINS / 4;                 // 512
    const int rot = (blockIdx.x * 4) & (nq - 1);
    for (int i = threadIdx.x; i < nq; i += 256) {
        int b = (i + rot) & (nq - 1);
        uint4 v = lh4[b];
        if (v.x) atomicAdd(&gp[4 * b + 0], v.x);
        if (v.y) atomicAdd(&gp[4 * b + 1], v.y);
        if (v.z) atomicAdd(&gp[4 * b + 2], v.z);
        if (v.w) atomicAdd(&gp[4 * b + 3], v.w);
    }
}

// ---------------------------------------------------------------------------
// Pass 2 (single block, 256 threads): each thread owns an 8-bin chunk; sums
// the NPART partials UNPACKED (final per-class counts can exceed 16 bits),
// Hillis-Steele scan for the descending positive prefix, then the bin-wise
// pAUC sum:  contribution = ng * E_f~U(0,1)[ max(0, (CP - 0.95P) + p*f) ]
// pAUC = S/(P*Ng);  loss = 0.5*CE_mean + 0.5*(1 - clip(pAUC/0.1,0,1)^2)
// ---------------------------------------------------------------------------
__global__ __launch_bounds__(256) void pass2_kernel(
    const unsigned int* __restrict__ hist, const double* __restrict__ ce_sum,
    const unsigned int* __restrict__ pos_cnt, float* __restrict__ out, int n)
{
    __shared__ double chunk_pos[256];
    __shared__ double sred[256];

    const int tid = threadIdx.x;
    const int lo  = HIST_BINS - (tid + 1) * 8;    // thread's 8-bin chunk

    // accumulate unpacked class counts across NPART partials
    unsigned int pos[8] = {0,0,0,0,0,0,0,0};
    unsigned int neg[8] = {0,0,0,0,0,0,0,0};
    const uint4* h4 = (const uint4*)hist;
#pragma unroll
    for (int p = 0; p < NPART; ++p) {
#pragma unroll
        for (int j = 0; j < 2; ++j) {
            uint4 v = h4[p * (HIST_BINS / 4) + lo / 4 + j];
            pos[4*j+0] += v.x >> 16;  neg[4*j+0] += v.x & 0xFFFFu;
            pos[4*j+1] += v.y >> 16;  neg[4*j+1] += v.y & 0xFFFFu;
            pos[4*j+2] += v.z >> 16;  neg[4*j+2] += v.z & 0xFFFFu;
            pos[4*j+3] += v.w >> 16;  neg[4*j+3] += v.w & 0xFFFFu;
        }
    }

    // phase 1: positives per chunk
    double psum = 0.0;
#pragma unroll
    for (int i = 0; i < 8; ++i) psum += (double)pos[i];
    chunk_pos[tid] = psum;
    __syncthreads();

    // phase 2: Hillis-Steele inclusive scan over descending-chunk order
    double v = psum;
    for (int s = 1; s < 256; s <<= 1) {
        double add = (tid >= s) ? chunk_pos[tid - s] : 0.0;
        __syncthreads();
        v += add;
        chunk_pos[tid] = v;
        __syncthreads();
    }
    double CP = v - psum;   // exclusive prefix: positives strictly above chunk

    const unsigned int P = *pos_cnt;
    const double T = RECALL_LO_C * (double)P;

    // phase 3: walk chunk descending (bin lo+i, i = 7..0)
    double S = 0.0;
#pragma unroll
    for (int i = 7; i >= 0; --i) {
        double p  = (double)pos[i];
        double ng = (double)neg[i];
        if (ng > 0.0) {
            double a = CP - T;
            double contrib;
            if (a >= 0.0) {
                contrib = a + 0.5 * p;
            } else {
                double ac = a + p;
                contrib = (ac > 0.0 && p > 0.0) ? (ac * ac) / (2.0 * p) : 0.0;
            }
            S += ng * contrib;
        }
        CP += p;
    }
    sred[tid] = S;
    __syncthreads();
    for (int s = 128; s > 0; s >>= 1) {
        if (tid < s) sred[tid] += sred[tid + s];
        __syncthreads();
    }

    if (tid == 0) {
        double Ng = (double)n - (double)P;
        double pauc = 0.0;
        if (P > 0 && Ng > 0.0) pauc = sred[0] / ((double)P * Ng);
        double avg = pauc / (2.0 * (1.0 - RECALL_LO_C));   // pauc / 0.1
        avg = fmin(fmax(avg, 0.0), 1.0);
        double ce = *ce_sum / (double)n;
        out[0] = (float)(0.5 * ce + 0.5 * (1.0 - avg * avg));
    }
}

extern "C" void kernel_launch(void* const* d_in, const int* in_sizes, int n_in,
                              void* d_out, int out_size, void* d_ws, size_t ws_size,
                              hipStream_t stream)
{
    const float* pred = (const float*)d_in[0];
    const int*   tgt  = (const int*)d_in[1];
    const int n = in_sizes[0];  // predictions is (N,1) -> N elements

    unsigned int* ghist   = (unsigned int*)d_ws;                        // NPART x HIST_BINS
    double*       ce_sum  = (double*)((char*)d_ws + NPART * HIST_BYTES);
    unsigned int* pos_cnt = (unsigned int*)((char*)d_ws + NPART * HIST_BYTES + 8);

    hipMemsetAsync(d_ws, 0, NPART * HIST_BYTES + 16, stream);

    pass1_kernel<<<GRID1, 256, 0, stream>>>(pred, tgt, ghist, ce_sum, pos_cnt, n);
    pass2_kernel<<<1, 256, 0, stream>>>(ghist, ce_sum, pos_cnt, (float*)d_out, n);
}